// Round 11
// baseline (18.974 us; speedup 1.0000x reference)
//
#include <hip/hip_runtime.h>
#include <hip/hip_bf16.h>

#define IMG 384
#define KR 4
#define TW 16      // tile width
#define TH 8       // tile height (4 vertical pixel-pairs, ty 0..3)
#define HW 24      // halo width
#define HH 16      // halo height
#define PST 37     // odd row stride (dwords): addr%32 = 74*ty+tx+j -> max 2-way (free)
#define PLANE (IMG*IMG)

__global__ __launch_bounds__(192) void abf_kernel(
    const float* __restrict__ input,   // [2][3][384][384]
    const float* __restrict__ sigmas,  // [2][2][384][384]
    float* __restrict__ out)           // [2][3][384][384]
{
    __shared__ float s_in[3 * HH * PST];     // 7.1 KB, channel-planar scalar
    __shared__ float s_comb[2][64][9];       // 4.6 KB, tz=1,2 partials (stride 9: conflict-lite)

    const int b      = blockIdx.z;
    const int tile_x = blockIdx.x * TW;
    const int tile_y = blockIdx.y * TH;
    const int tx = threadIdx.x;   // 0..15 column
    const int ty = threadIdx.y;   // 0..3  pixel-pair (rows 2ty, 2ty+1)
    const int tz = threadIdx.z;   // 0..2  dy-group (wave-uniform)
    const int tid = tz * 64 + ty * TW + tx;

    // ---- stage 24x16 halo, scalar, div once, add-only loops ----
    {
        const int sy = tid / HW;          // 0..7
        const int sx = tid - sy * HW;     // 0..23
        const int gx = tile_x + sx - KR;
        const bool okx = (gx >= 0) & (gx < IMG);
        const float* inb = input + (size_t)b * 3 * PLANE;
        #pragma unroll
        for (int c = 0; c < 3; ++c) {
            #pragma unroll
            for (int k = 0; k < 2; ++k) {
                const int y  = sy + 8 * k;
                const int gy = tile_y + y - KR;
                float v = 0.f;
                if (okx & (gy >= 0) & (gy < IMG))
                    v = inb[c * PLANE + (gy << 8) + (gy << 7) + gx];   // gy*384+gx
                s_in[(c * HH + y) * PST + sx] = v;
            }
        }
    }
    __syncthreads();

    const int ox  = tile_x + tx;
    const int YA  = tile_y + 2 * ty;                // pixel A row; B = YA+1
    const int siA = (YA << 8) + (YA << 7) + ox;     // YA*384 + ox

    const float* sgb = sigmas + (size_t)b * 2 * PLANE;
    const float isa = __builtin_amdgcn_rcpf(fabsf(sgb[siA])         + 1e-12f);
    const float isb = __builtin_amdgcn_rcpf(fabsf(sgb[siA + IMG])   + 1e-12f);
    const float ira = __builtin_amdgcn_rcpf(fabsf(sgb[PLANE + siA]) + 1e-12f);
    const float irb = __builtin_amdgcn_rcpf(fabsf(sgb[PLANE + siA + IMG]) + 1e-12f);
    // w = exp2(dsq*B + (rx2+ry2)*A) per pixel
    const float Aa = -0.72134752f * isa * isa, Ab = -0.72134752f * isb * isb;
    const float Ba = -0.72134752f * ira * ira, Bb = -0.72134752f * irb * irb;

    // centers: halo rows 2ty+4 (A), 2ty+5 (B), col tx+4
    const int ccb = (2 * ty + 4) * PST + tx + 4;
    const float cA0 = s_in[0 * HH * PST + ccb],       cB0 = s_in[0 * HH * PST + ccb + PST];
    const float cA1 = s_in[1 * HH * PST + ccb],       cB1 = s_in[1 * HH * PST + ccb + PST];
    const float cA2 = s_in[2 * HH * PST + ccb],       cB2 = s_in[2 * HH * PST + ccb + PST];

    float wsA = 0.f, aA0 = 0.f, aA1 = 0.f, aA2 = 0.f;
    float wsB = 0.f, aB0 = 0.f, aB1 = 0.f, aB2 = 0.f;

    auto loadrow = [&](float (&dst)[3][9], int hy) {
        const int base = hy * PST + tx;
        #pragma unroll
        for (int c = 0; c < 3; ++c)
            #pragma unroll
            for (int j = 0; j < 9; ++j)
                dst[c][j] = s_in[c * HH * PST + base + j];
    };

    auto dotaps = [&](const float (&ra)[3][9], const float (&rb)[3][9], int dy) {
        const float ry  = (float)(dy - KR);
        const float sya = ry * ry * Aa;
        const float syb = ry * ry * Ab;
        #pragma unroll
        for (int dx = 0; dx < 9; ++dx) {
            const float rx2 = (float)((dx - KR) * (dx - KR));
            // pixel A (independent chain 1)
            const float va0 = ra[0][dx], va1 = ra[1][dx], va2 = ra[2][dx];
            const float da0 = va0 - cA0, da1 = va1 - cA1, da2 = va2 - cA2;
            const float dsa = fmaf(da0, da0, fmaf(da1, da1, da2 * da2));
            const float wa  = __builtin_amdgcn_exp2f(fmaf(dsa, Ba, fmaf(rx2, Aa, sya)));
            wsA += wa; aA0 = fmaf(wa, va0, aA0); aA1 = fmaf(wa, va1, aA1); aA2 = fmaf(wa, va2, aA2);
            // pixel B (independent chain 2)
            const float vb0 = rb[0][dx], vb1 = rb[1][dx], vb2 = rb[2][dx];
            const float db0 = vb0 - cB0, db1 = vb1 - cB1, db2 = vb2 - cB2;
            const float dsb = fmaf(db0, db0, fmaf(db1, db1, db2 * db2));
            const float wb  = __builtin_amdgcn_exp2f(fmaf(dsb, Bb, fmaf(rx2, Ab, syb)));
            wsB += wb; aB0 = fmaf(wb, vb0, aB0); aB1 = fmaf(wb, vb1, aB1); aB2 = fmaf(wb, vb2, aB2);
        }
    };

    // tz's dy-group {3tz..3tz+2}: A reads halo rows R..R+2, B reads R+1..R+3.
    // Two row-windows pipelined: each of the 4 rows loaded from LDS exactly once.
    {
        const int R = 2 * ty + 3 * tz;
        float rA[3][9], rB[3][9];
        loadrow(rA, R);
        loadrow(rB, R + 1);
        dotaps(rA, rB, 3 * tz);          // A<-R,   B<-R+1
        loadrow(rA, R + 2);
        dotaps(rB, rA, 3 * tz + 1);      // A<-R+1, B<-R+2
        loadrow(rB, R + 3);
        dotaps(rA, rB, 3 * tz + 2);      // A<-R+2, B<-R+3
    }

    const int pid = ty * TW + tx;   // 0..63
    if (tz > 0) {
        float* d = s_comb[tz - 1][pid];
        d[0] = wsA; d[1] = aA0; d[2] = aA1; d[3] = aA2;
        d[4] = wsB; d[5] = aB0; d[6] = aB1; d[7] = aB2;
    }
    __syncthreads();

    if (tz == 0) {
        #pragma unroll
        for (int t = 0; t < 2; ++t) {
            const float* s = s_comb[t][pid];
            wsA += s[0]; aA0 += s[1]; aA1 += s[2]; aA2 += s[3];
            wsB += s[4]; aB0 += s[5]; aB1 += s[6]; aB2 += s[7];
        }
        const float ivA = __builtin_amdgcn_rcpf(wsA);   // wsum >= 1 (center w == 1)
        const float ivB = __builtin_amdgcn_rcpf(wsB);
        float* outb = out + (size_t)b * 3 * PLANE;
        outb[siA]             = aA0 * ivA;  outb[siA + IMG]             = aB0 * ivB;
        outb[PLANE + siA]     = aA1 * ivA;  outb[PLANE + siA + IMG]     = aB1 * ivB;
        outb[2 * PLANE + siA] = aA2 * ivA;  outb[2 * PLANE + siA + IMG] = aB2 * ivB;
    }
}

extern "C" void kernel_launch(void* const* d_in, const int* in_sizes, int n_in,
                              void* d_out, int out_size, void* d_ws, size_t ws_size,
                              hipStream_t stream) {
    const float* input  = (const float*)d_in[0];
    const float* sigmas = (const float*)d_in[1];
    float* out = (float*)d_out;

    dim3 block(TW, TH / 2, 3);            // (16,4,3) = 192 threads, 3 waves
    dim3 grid(IMG / TW, IMG / TH, 2);     // 24 x 48 x 2 = 2304 blocks (9/CU exact)
    abf_kernel<<<grid, block, 0, stream>>>(input, sigmas, out);
}

// Round 12
// 15.517 us; speedup vs baseline: 1.2228x; 1.2228x over previous
//
#include <hip/hip_runtime.h>
#include <hip/hip_bf16.h>

typedef float f32x2 __attribute__((ext_vector_type(2)));

#define IMG 384
#define KR 4
#define TW 16      // tile width (16 columns, 1 per thread-x)
#define TH 8       // tile height (each thread owns rows Y, Y+1 -> ty 0..3)
#define HW 24      // halo width
#define HH 16      // halo height
#define PRS 25     // pair-row stride in float2 units (odd -> 4-touch/bank floor, verified)
#define NE 8       // even-start row pairs: (0,1),(2,3),...,(14,15)
#define NO 7       // odd-start  row pairs: (1,2),(3,4),...,(13,14)
#define PLANE (IMG*IMG)

static __device__ __forceinline__ f32x2 mk2(float a, float b) { f32x2 r; r.x = a; r.y = b; return r; }

__global__ __launch_bounds__(192) void abf_kernel(
    const float* __restrict__ input,   // [2][3][384][384]
    const float* __restrict__ sigmas,  // [2][2][384][384]
    float* __restrict__ out)           // [2][3][384][384]
{
    __shared__ f32x2 sE[3 * NE * PRS];          // 4.8 KB: pairs starting at even halo rows
    __shared__ f32x2 sO[3 * NO * PRS];          // 4.2 KB: pairs starting at odd halo rows
    __shared__ f32x2 s_comb[2][TW * (TH/2)][4]; // 4 KB: tz=1,2 partial sums

    const int b      = blockIdx.z;
    const int tile_x = blockIdx.x * TW;
    const int tile_y = blockIdx.y * TH;
    const int tx = threadIdx.x;   // 0..15 column
    const int ty = threadIdx.y;   // 0..3  row-pair
    const int tz = threadIdx.z;   // 0..2  dy-group (wave-uniform)
    const int tid = tz * 64 + ty * TW + tx;

    // ---- stage 24x16 halo into BOTH parity copies (each value written <=2x) ----
    {
        const int sy = tid / HW;          // 0..7 (one magic-mul)
        const int sx = tid - sy * HW;     // 0..23
        const int gx = tile_x + sx - KR;
        const bool okx = (gx >= 0) & (gx < IMG);
        const float* inb = input + (size_t)b * 3 * PLANE;
        float* fE = (float*)sE;
        float* fO = (float*)sO;
        #pragma unroll
        for (int c = 0; c < 3; ++c) {
            #pragma unroll
            for (int k = 0; k < 2; ++k) {
                const int hy = sy + 8 * k;            // 0..15
                const int gy = tile_y + hy - KR;
                float v = 0.f;
                if (okx & (gy >= 0) & (gy < IMG))
                    v = inb[c * PLANE + (gy << 8) + (gy << 7) + gx];   // gy*384 + gx
                fE[((c * NE + (hy >> 1)) * PRS + sx) * 2 + (hy & 1)] = v;
                if (hy >= 1 && hy <= 14)
                    fO[((c * NO + ((hy - 1) >> 1)) * PRS + sx) * 2 + ((hy - 1) & 1)] = v;
            }
        }
    }
    __syncthreads();

    const int ox  = tile_x + tx;
    const int oyA = tile_y + 2 * ty;                 // pixel A row; pixel B = oyA+1
    const int siA = (oyA << 8) + (oyA << 7) + ox;    // oyA*384 + ox

    const float* sgb = sigmas + (size_t)b * 2 * PLANE;
    const float ssA = sgb[siA],         ssB = sgb[siA + IMG];
    const float srA = sgb[PLANE + siA], srB = sgb[PLANE + siA + IMG];
    const float isA = __builtin_amdgcn_rcpf(fabsf(ssA) + 1e-12f);
    const float isB = __builtin_amdgcn_rcpf(fabsf(ssB) + 1e-12f);
    const float irA = __builtin_amdgcn_rcpf(fabsf(srA) + 1e-12f);
    const float irB = __builtin_amdgcn_rcpf(fabsf(srB) + 1e-12f);
    // w = exp2(dsq*B + (rx2+ry2)*A), packed over the two (vertical) pixels
    const f32x2 A = mk2(-0.72134752f * isA * isA, -0.72134752f * isB * isB);
    const f32x2 B = mk2(-0.72134752f * irA * irA, -0.72134752f * irB * irB);

    // centers: halo rows (2ty+4, 2ty+5) = even-start pair (ty+2), col tx+4 -> aligned f32x2
    const f32x2 cen0 = sE[(0 * NE + ty + 2) * PRS + tx + 4];
    const f32x2 cen1 = sE[(1 * NE + ty + 2) * PRS + tx + 4];
    const f32x2 cen2 = sE[(2 * NE + ty + 2) * PRS + tx + 4];

    f32x2 wsum = mk2(0.f, 0.f), a0 = wsum, a1 = wsum, a2 = wsum;

    // tz handles dy in {3tz, 3tz+1, 3tz+2}; tap (dy,dx) = pair starting at halo row 2ty+dy
    #pragma unroll 1
    for (int r = 0; r < 3; ++r) {
        const int dy = tz * 3 + r;
        const float ry = (float)(dy - KR);
        const f32x2 syA = (ry * ry) * A;

        const f32x2 *p0, *p1, *p2;          // wave-uniform parity select
        if (dy & 1) {
            const int pr = ty + ((dy - 1) >> 1);
            p0 = &sO[(0 * NO + pr) * PRS + tx];
            p1 = &sO[(1 * NO + pr) * PRS + tx];
            p2 = &sO[(2 * NO + pr) * PRS + tx];
        } else {
            const int pr = ty + (dy >> 1);
            p0 = &sE[(0 * NE + pr) * PRS + tx];
            p1 = &sE[(1 * NE + pr) * PRS + tx];
            p2 = &sE[(2 * NE + pr) * PRS + tx];
        }

        // window: 9 aligned f32x2 per channel (ds_read_b64/b128-mergeable, conflict-free)
        f32x2 w0[9], w1[9], w2[9];
        #pragma unroll
        for (int j = 0; j < 9; ++j) { w0[j] = p0[j]; w1[j] = p1[j]; w2[j] = p2[j]; }

        #pragma unroll
        for (int dx = 0; dx < 9; ++dx) {
            const float rx2 = (float)((dx - KR) * (dx - KR));
            const f32x2 v0 = w0[dx], v1 = w1[dx], v2 = w2[dx];
            const f32x2 d0 = v0 - cen0;
            const f32x2 d1 = v1 - cen1;
            const f32x2 d2 = v2 - cen2;
            const f32x2 dsq = d0 * d0 + d1 * d1 + d2 * d2;   // pk mul + 2 pk fma
            const f32x2 arg = dsq * B + (rx2 * A + syA);     // pk fma chain
            const f32x2 w = mk2(__builtin_amdgcn_exp2f(arg.x),
                                __builtin_amdgcn_exp2f(arg.y));
            wsum += w;
            a0 += w * v0;
            a1 += w * v1;
            a2 += w * v2;
        }
    }

    const int pid = ty * TW + tx;   // 0..63
    if (tz > 0) {
        s_comb[tz - 1][pid][0] = wsum;
        s_comb[tz - 1][pid][1] = a0;
        s_comb[tz - 1][pid][2] = a1;
        s_comb[tz - 1][pid][3] = a2;
    }
    __syncthreads();

    if (tz == 0) {
        #pragma unroll
        for (int t = 0; t < 2; ++t) {
            wsum += s_comb[t][pid][0];
            a0   += s_comb[t][pid][1];
            a1   += s_comb[t][pid][2];
            a2   += s_comb[t][pid][3];
        }
        const f32x2 inv = mk2(__builtin_amdgcn_rcpf(wsum.x),
                              __builtin_amdgcn_rcpf(wsum.y));   // wsum >= 1 (center w == 1)
        float* outb = out + (size_t)b * 3 * PLANE;
        const f32x2 o0 = a0 * inv, o1 = a1 * inv, o2 = a2 * inv;
        outb[siA]                 = o0.x;  outb[siA + IMG]             = o0.y;
        outb[PLANE + siA]         = o1.x;  outb[PLANE + siA + IMG]     = o1.y;
        outb[2 * PLANE + siA]     = o2.x;  outb[2 * PLANE + siA + IMG] = o2.y;
    }
}

extern "C" void kernel_launch(void* const* d_in, const int* in_sizes, int n_in,
                              void* d_out, int out_size, void* d_ws, size_t ws_size,
                              hipStream_t stream) {
    const float* input  = (const float*)d_in[0];
    const float* sigmas = (const float*)d_in[1];
    float* out = (float*)d_out;

    dim3 block(TW, TH / 2, 3);                      // (16,4,3) = 192 threads, 3 waves
    dim3 grid(IMG / TW, IMG / TH, 2);               // 24 x 48 x 2 = 2304 blocks (9/CU)
    abf_kernel<<<grid, block, 0, stream>>>(input, sigmas, out);
}